// Round 4
// baseline (74.061 us; speedup 1.0000x reference)
//
#include <hip/hip_runtime.h>

#define NV 1448
#define JD 4344    // 3*NV
#define CC 256
#define BB 64
#define QQ 128     // 2*BB
#define SLICE 181  // NV/8 columns per chamfer block (exact: 8*181=1448)
#define NROW (2 * BB * NV)  // 185344 row-slots (dir x b x row)
#define RPT 6      // rows per thread in chamfer (256*6=1536 >= 1448)

// ---------------------------------------------------------------------------
// K1: global average pool over H*W=64 -> latT[c][q], q = t*64+b
// ---------------------------------------------------------------------------
__global__ __launch_bounds__(256) void pool_kernel(const float* __restrict__ inp,
                                                   const float* __restrict__ tgt,
                                                   float* __restrict__ latT) {
    int gid  = blockIdx.x * 256 + threadIdx.x;
    int lane = gid & 15;
    int row  = gid >> 4;                          // (t,b,c) flat, 32768 rows
    if (row >= 2 * BB * CC) return;
    int t  = row >> 14;                           // BB*CC = 16384
    int bc = row & 16383;
    const float* src = (t ? tgt : inp) + (size_t)bc * 64;
    float4 v = reinterpret_cast<const float4*>(src)[lane];
    float s = (v.x + v.y) + (v.z + v.w);
    s += __shfl_xor(s, 1);
    s += __shfl_xor(s, 2);
    s += __shfl_xor(s, 4);
    s += __shfl_xor(s, 8);
    if (lane == 0) {
        int b = bc >> 8, c = bc & 255;
        latT[c * QQ + t * BB + b] = s * (1.0f / 64.0f);
    }
}

// ---------------------------------------------------------------------------
// K2: decode GEMM  pts3[q][j] = sum_c delta_L[j][c]*latT[c][q] + mu_L[j]
// ---------------------------------------------------------------------------
__global__ __launch_bounds__(512) void decode_kernel(const float* __restrict__ latT,
                                                     const float* __restrict__ muL,
                                                     const float* __restrict__ deltaL,
                                                     const float* __restrict__ muR,
                                                     const float* __restrict__ deltaR,
                                                     const int* __restrict__ labels,
                                                     float* __restrict__ pts3) {
    const int jt = blockIdx.x;                 // 136 tiles
    const int L  = blockIdx.y;                 // 0=left, 1=right
    const float* __restrict__ delta = L ? deltaR : deltaL;
    const float* __restrict__ mu    = L ? muR : muL;
    const int j0  = jt * 32;
    const int tid = threadIdx.x;
    const int jl  = tid & 31;
    const int qg  = tid >> 5;                  // 0..15

    __shared__ float As[32][36];
    __shared__ float Bs[32][QQ];

    float acc[8];
#pragma unroll
    for (int i = 0; i < 8; ++i) acc[i] = 0.f;

    for (int kc = 0; kc < CC; kc += 32) {
        __syncthreads();
        if (tid < 256) {                        // stage A: 32 rows x 32 k
            int r = tid >> 3;
            int i = tid & 7;
            int j = j0 + r;
            float4 v = make_float4(0.f, 0.f, 0.f, 0.f);
            if (j < JD)
                v = *reinterpret_cast<const float4*>(delta + (size_t)j * CC + kc + i * 4);
            *reinterpret_cast<float4*>(&As[r][i * 4]) = v;
        }
        {                                       // stage B: 32 x 128 floats
            const float4* src = reinterpret_cast<const float4*>(latT + (size_t)kc * QQ);
            float4* dst = reinterpret_cast<float4*>(&Bs[0][0]);
            dst[tid]       = src[tid];
            dst[tid + 512] = src[tid + 512];
        }
        __syncthreads();

#pragma unroll
        for (int k4 = 0; k4 < 32; k4 += 4) {
            float4 av = *reinterpret_cast<const float4*>(&As[jl][k4]);
            float a[4] = {av.x, av.y, av.z, av.w};
#pragma unroll
            for (int kk = 0; kk < 4; ++kk) {
                const float4* bp = reinterpret_cast<const float4*>(&Bs[k4 + kk][qg * 8]);
                float4 b0 = bp[0], b1 = bp[1];
                float ak = a[kk];
                acc[0] = fmaf(ak, b0.x, acc[0]);
                acc[1] = fmaf(ak, b0.y, acc[1]);
                acc[2] = fmaf(ak, b0.z, acc[2]);
                acc[3] = fmaf(ak, b0.w, acc[3]);
                acc[4] = fmaf(ak, b1.x, acc[4]);
                acc[5] = fmaf(ak, b1.y, acc[5]);
                acc[6] = fmaf(ak, b1.z, acc[6]);
                acc[7] = fmaf(ak, b1.w, acc[7]);
            }
        }
    }

    int j = j0 + jl;
    if (j < JD) {
        float base = mu[j];
#pragma unroll
        for (int i = 0; i < 8; ++i) {
            int q = qg * 8 + i;
            int b = q & 63;
            if (labels[b] == L) pts3[(size_t)q * JD + j] = acc[i] + base;
        }
    }
}

// ---------------------------------------------------------------------------
// K3: chamfer partial row-mins, pack fused in. grid (slice 0..7, b, dir) =
// 1024 blocks = 4/CU exact. Each thread owns 6 rows (A in registers); B
// slice (181 cols) staged in LDS pre-scaled (-2x,-2y,-2z,|b|^2). One
// ds_read_b128 broadcast now feeds 6 rows -> LDS pipe time /3 vs R3.
// min over d' = -2a.b + |b|^2; |a|^2 added at epilogue.
// ---------------------------------------------------------------------------
__global__ __launch_bounds__(256) void chamfer_kernel(const float* __restrict__ pts3,
                                                      float* __restrict__ pmin) {
    const int slice = blockIdx.x;
    const int b     = blockIdx.y;
    const int dir   = blockIdx.z;
    const int qa = dir * BB + b;
    const int qb = (1 - dir) * BB + b;
    const float* __restrict__ A3 = pts3 + (size_t)qa * JD;
    const float* __restrict__ B3 = pts3 + (size_t)qb * JD + slice * (SLICE * 3);

    __shared__ float4 Bs[SLICE];
    const int tid = threadIdx.x;
    if (tid < SLICE) {
        float x = B3[3 * tid], y = B3[3 * tid + 1], z = B3[3 * tid + 2];
        Bs[tid] = make_float4(-2.f * x, -2.f * y, -2.f * z, fmaf(x, x, fmaf(y, y, z * z)));
    }
    __syncthreads();

    float ax[RPT], ay[RPT], az[RPT], aw[RPT], mn[RPT];
#pragma unroll
    for (int r = 0; r < RPT; ++r) {
        int row = tid + 256 * r;
        bool v = row < NV;
        float x = v ? A3[3 * row]     : 0.f;
        float y = v ? A3[3 * row + 1] : 0.f;
        float z = v ? A3[3 * row + 2] : 0.f;
        ax[r] = x; ay[r] = y; az[r] = z;
        aw[r] = fmaf(x, x, fmaf(y, y, z * z));
        mn[r] = 1e30f;
    }

    for (int m = 0; m < SLICE - 1; m += 2) {
        float4 b0 = Bs[m];
        float4 b1 = Bs[m + 1];
#pragma unroll
        for (int r = 0; r < RPT; ++r) {
            float d0 = fmaf(b0.x, ax[r], fmaf(b0.y, ay[r], fmaf(b0.z, az[r], b0.w)));
            float d1 = fmaf(b1.x, ax[r], fmaf(b1.y, ay[r], fmaf(b1.z, az[r], b1.w)));
            mn[r] = fminf(fminf(mn[r], d0), d1);   // -> v_min3_f32
        }
    }
    {   // tail column (SLICE is odd)
        float4 b0 = Bs[SLICE - 1];
#pragma unroll
        for (int r = 0; r < RPT; ++r) {
            float d0 = fmaf(b0.x, ax[r], fmaf(b0.y, ay[r], fmaf(b0.z, az[r], b0.w)));
            mn[r] = fminf(mn[r], d0);
        }
    }

    float* dst = pmin + (size_t)slice * NROW + (size_t)qa * NV;
#pragma unroll
    for (int r = 0; r < RPT; ++r) {
        int row = tid + 256 * r;
        if (row < NV) dst[row] = mn[r] + aw[r];
    }
}

// ---------------------------------------------------------------------------
// K4: combine 8 slice-mins, sqrt, block sums -> exact fixed-point atomic
// accumulate (order-independent => deterministic); last block writes out.
// 362 blocks x 256 threads x 2 rows = 185344 rows exactly.
// ---------------------------------------------------------------------------
__global__ __launch_bounds__(256) void combine_kernel(const float* __restrict__ pmin,
                                                      unsigned long long* __restrict__ acc,
                                                      float* __restrict__ out) {
    int g0 = blockIdx.x * 512 + threadIdx.x;
    int g1 = g0 + 256;
    float v0 = 1e30f, v1 = 1e30f;
#pragma unroll
    for (int k = 0; k < 8; ++k) {
        v0 = fminf(v0, pmin[g0 + (size_t)k * NROW]);
        v1 = fminf(v1, pmin[g1 + (size_t)k * NROW]);
    }
    float s = sqrtf(fmaxf(v0, 1e-12f)) + sqrtf(fmaxf(v1, 1e-12f));
    s += __shfl_xor(s, 1);
    s += __shfl_xor(s, 2);
    s += __shfl_xor(s, 4);
    s += __shfl_xor(s, 8);
    s += __shfl_xor(s, 16);
    s += __shfl_xor(s, 32);
    __shared__ float wsum[4];
    if ((threadIdx.x & 63) == 0) wsum[threadIdx.x >> 6] = s;
    __syncthreads();
    if (threadIdx.x == 0) {
        float bs = wsum[0] + wsum[1] + wsum[2] + wsum[3];
        unsigned long long q = (unsigned long long)((double)bs * 16777216.0); // 2^24 fixed point
        atomicAdd(acc, q);
        __threadfence();
        unsigned long long done = atomicAdd(acc + 1, 1ull);
        if (done == 361) {  // last block
            __threadfence();
            unsigned long long total = atomicAdd(acc, 0ull);
            out[0] = (float)((double)total * (0x1p-24 / (64.0 * 1448.0)));
        }
    }
}

extern "C" void kernel_launch(void* const* d_in, const int* in_sizes, int n_in,
                              void* d_out, int out_size, void* d_ws, size_t ws_size,
                              hipStream_t stream) {
    const float* inp    = (const float*)d_in[0];
    const float* tgt    = (const float*)d_in[1];
    const int*   labels = (const int*)d_in[2];
    const float* muL    = (const float*)d_in[3];
    const float* deltaL = (const float*)d_in[4];
    const float* muR    = (const float*)d_in[5];
    const float* deltaR = (const float*)d_in[6];
    float* out = (float*)d_out;

    char* ws = (char*)d_ws;
    float* latT = (float*)ws;                                    // 128 KB
    float* pts3 = (float*)(ws + (128 << 10));                    // 128*4344*4 = 2224128 B
    float* pmin = (float*)(ws + (128 << 10) + 2224128);          // 8*185344*4 = 5931008 B
    unsigned long long* acc = (unsigned long long*)(ws + (128 << 10) + 2224128 + 5931008);

    hipMemsetAsync(acc, 0, 16, stream);  // zero {sum, counter} each call (captured as node)
    hipLaunchKernelGGL(pool_kernel, dim3(2048), dim3(256), 0, stream, inp, tgt, latT);
    hipLaunchKernelGGL(decode_kernel, dim3(136, 2, 1), dim3(512), 0, stream,
                       latT, muL, deltaL, muR, deltaR, labels, pts3);
    hipLaunchKernelGGL(chamfer_kernel, dim3(8, 64, 2), dim3(256), 0, stream,
                       pts3, pmin);
    hipLaunchKernelGGL(combine_kernel, dim3(362), dim3(256), 0, stream, pmin, acc, out);
}

// Round 5
// 67.088 us; speedup vs baseline: 1.1039x; 1.1039x over previous
//
#include <hip/hip_runtime.h>

#define NV 1448
#define JD 4344    // 3*NV
#define CC 256
#define BB 64
#define QQ 128     // 2*BB
#define SLICE 181  // NV/8 cols per chamfer block
#define NROW (2 * BB * NV)  // 185344 row-slots
#define RPT 12     // rows per thread in chamfer (128*12=1536 >= 1448)

// ---------------------------------------------------------------------------
// K1: global average pool -> latT[c][q], q = t*64+b. Thread 0 zeroes acc.
// ---------------------------------------------------------------------------
__global__ __launch_bounds__(256) void pool_kernel(const float* __restrict__ inp,
                                                   const float* __restrict__ tgt,
                                                   float* __restrict__ latT,
                                                   unsigned long long* __restrict__ acc) {
    int gid  = blockIdx.x * 256 + threadIdx.x;
    if (gid == 0) { acc[0] = 0ull; acc[1] = 0ull; }
    int lane = gid & 15;
    int row  = gid >> 4;
    if (row >= 2 * BB * CC) return;
    int t  = row >> 14;
    int bc = row & 16383;
    const float* src = (t ? tgt : inp) + (size_t)bc * 64;
    float4 v = reinterpret_cast<const float4*>(src)[lane];
    float s = (v.x + v.y) + (v.z + v.w);
    s += __shfl_xor(s, 1);
    s += __shfl_xor(s, 2);
    s += __shfl_xor(s, 4);
    s += __shfl_xor(s, 8);
    if (lane == 0) {
        int b = bc >> 8, c = bc & 255;
        latT[c * QQ + t * BB + b] = s * (1.0f / 64.0f);
    }
}

// ---------------------------------------------------------------------------
// K2: decode GEMM, 4j x 4q register blocking (16 acc/thread).
// grid (jt 0..67, L 0..1, qh 0..1), 256 threads.
// jl = tid&15 -> j = j0 + jl*4 + u;  qg = tid>>4 -> q = qh*64 + qg*4 + v.
// AsT[k][j] / Bs[k][q] in LDS; both inner reads are float4 (b128):
// 8 LDS reads per 64 FMA (was 9 per 32).
// ---------------------------------------------------------------------------
__global__ __launch_bounds__(256) void decode_kernel(const float* __restrict__ latT,
                                                     const float* __restrict__ muL,
                                                     const float* __restrict__ deltaL,
                                                     const float* __restrict__ muR,
                                                     const float* __restrict__ deltaR,
                                                     const int* __restrict__ labels,
                                                     float* __restrict__ pts3) {
    const int jt = blockIdx.x;                 // 68 tiles of 64 j
    const int L  = blockIdx.y;
    const int qh = blockIdx.z;                 // q half: 64 q's
    const float* __restrict__ delta = L ? deltaR : deltaL;
    const float* __restrict__ mu    = L ? muR : muL;
    const int j0  = jt * 64;
    const int tid = threadIdx.x;
    const int jl  = tid & 15;
    const int qg  = tid >> 4;                  // 0..15

    __shared__ float AsT[32][64];              // [k][j]
    __shared__ float Bs[32][64];               // [k][q]

    float acc[4][4];
#pragma unroll
    for (int u = 0; u < 4; ++u)
#pragma unroll
        for (int v = 0; v < 4; ++v) acc[u][v] = 0.f;

    const int sj = tid & 63;                   // stage: j-lane
    const int sk = (tid >> 6) * 8;             // stage: k-base (0,8,16,24)
    const float4* latT4 = reinterpret_cast<const float4*>(latT);

    for (int kc = 0; kc < CC; kc += 32) {
        __syncthreads();
        {   // stage AsT: 64 j x 32 k
            int j = j0 + sj;
            float4 v0 = make_float4(0.f, 0.f, 0.f, 0.f), v1 = v0;
            if (j < JD) {
                const float4* dp = reinterpret_cast<const float4*>(delta + (size_t)j * CC + kc + sk);
                v0 = dp[0]; v1 = dp[1];
            }
            AsT[sk + 0][sj] = v0.x; AsT[sk + 1][sj] = v0.y;
            AsT[sk + 2][sj] = v0.z; AsT[sk + 3][sj] = v0.w;
            AsT[sk + 4][sj] = v1.x; AsT[sk + 5][sj] = v1.y;
            AsT[sk + 6][sj] = v1.z; AsT[sk + 7][sj] = v1.w;
        }
        {   // stage Bs: 32 k x 64 q = 512 float4, 2 per thread
            int k  = tid >> 4;                 // 0..15
            int qi = tid & 15;                 // float4 index within row
            reinterpret_cast<float4*>(&Bs[k][0])[qi]      = latT4[(size_t)(kc + k) * 32 + qh * 16 + qi];
            reinterpret_cast<float4*>(&Bs[k + 16][0])[qi] = latT4[(size_t)(kc + k + 16) * 32 + qh * 16 + qi];
        }
        __syncthreads();

#pragma unroll
        for (int k4 = 0; k4 < 32; k4 += 4) {
#pragma unroll
            for (int kk = 0; kk < 4; ++kk) {
                float4 a = *reinterpret_cast<const float4*>(&AsT[k4 + kk][jl * 4]);
                float4 b = *reinterpret_cast<const float4*>(&Bs[k4 + kk][qg * 4]);
                float av[4] = {a.x, a.y, a.z, a.w};
                float bv[4] = {b.x, b.y, b.z, b.w};
#pragma unroll
                for (int u = 0; u < 4; ++u)
#pragma unroll
                    for (int v = 0; v < 4; ++v)
                        acc[u][v] = fmaf(av[u], bv[v], acc[u][v]);
            }
        }
    }

    int j = j0 + jl * 4;
    if (j < JD) {   // full quad or nothing (4344 % 4 == 0)
        float4 m = *reinterpret_cast<const float4*>(mu + j);
        float mu4[4] = {m.x, m.y, m.z, m.w};
#pragma unroll
        for (int v = 0; v < 4; ++v) {
            int q = qh * 64 + qg * 4 + v;
            int b = q & 63;
            if (labels[b] == L) {
                float4 o = make_float4(acc[0][v] + mu4[0], acc[1][v] + mu4[1],
                                       acc[2][v] + mu4[2], acc[3][v] + mu4[3]);
                *reinterpret_cast<float4*>(pts3 + (size_t)q * JD + j) = o;
            }
        }
    }
}

// ---------------------------------------------------------------------------
// K3: chamfer partial row-mins, pack fused. grid (slice 0..7, b, dir) = 1024
// blocks x 128 threads, 12 rows/thread: one LDS b128 broadcast feeds 12 rows.
// B slice pre-scaled (-2x,-2y,-2z,|b|^2); |a|^2 added at epilogue.
// ---------------------------------------------------------------------------
__global__ __launch_bounds__(128) void chamfer_kernel(const float* __restrict__ pts3,
                                                      float* __restrict__ pmin) {
    const int slice = blockIdx.x;
    const int b     = blockIdx.y;
    const int dir   = blockIdx.z;
    const int qa = dir * BB + b;
    const int qb = (1 - dir) * BB + b;
    const float* __restrict__ A3 = pts3 + (size_t)qa * JD;
    const float* __restrict__ B3 = pts3 + (size_t)qb * JD + slice * (SLICE * 3);

    __shared__ float4 Bs[SLICE];
    const int tid = threadIdx.x;
    for (int i = tid; i < SLICE; i += 128) {
        float x = B3[3 * i], y = B3[3 * i + 1], z = B3[3 * i + 2];
        Bs[i] = make_float4(-2.f * x, -2.f * y, -2.f * z, fmaf(x, x, fmaf(y, y, z * z)));
    }
    __syncthreads();

    float ax[RPT], ay[RPT], az[RPT], aw[RPT], mn[RPT];
#pragma unroll
    for (int r = 0; r < RPT; ++r) {
        int row = tid + 128 * r;
        bool v = row < NV;
        float x = v ? A3[3 * row]     : 0.f;
        float y = v ? A3[3 * row + 1] : 0.f;
        float z = v ? A3[3 * row + 2] : 0.f;
        ax[r] = x; ay[r] = y; az[r] = z;
        aw[r] = fmaf(x, x, fmaf(y, y, z * z));
        mn[r] = 1e30f;
    }

    for (int m = 0; m < SLICE - 1; m += 2) {
        float4 b0 = Bs[m];
        float4 b1 = Bs[m + 1];
#pragma unroll
        for (int r = 0; r < RPT; ++r) {
            float d0 = fmaf(b0.x, ax[r], fmaf(b0.y, ay[r], fmaf(b0.z, az[r], b0.w)));
            float d1 = fmaf(b1.x, ax[r], fmaf(b1.y, ay[r], fmaf(b1.z, az[r], b1.w)));
            mn[r] = fminf(fminf(mn[r], d0), d1);   // v_min3_f32
        }
    }
    {   // tail (SLICE odd)
        float4 b0 = Bs[SLICE - 1];
#pragma unroll
        for (int r = 0; r < RPT; ++r) {
            float d0 = fmaf(b0.x, ax[r], fmaf(b0.y, ay[r], fmaf(b0.z, az[r], b0.w)));
            mn[r] = fminf(mn[r], d0);
        }
    }

    float* dst = pmin + (size_t)slice * NROW + (size_t)qa * NV;
#pragma unroll
    for (int r = 0; r < RPT; ++r) {
        int row = tid + 128 * r;
        if (row < NV) dst[row] = mn[r] + aw[r];
    }
}

// ---------------------------------------------------------------------------
// K4: combine 8 slice-mins, sqrt, block sums -> exact fixed-point atomic
// accumulate (order-independent => deterministic); last block writes out.
// ---------------------------------------------------------------------------
__global__ __launch_bounds__(256) void combine_kernel(const float* __restrict__ pmin,
                                                      unsigned long long* __restrict__ acc,
                                                      float* __restrict__ out) {
    int g0 = blockIdx.x * 512 + threadIdx.x;
    int g1 = g0 + 256;
    float v0 = 1e30f, v1 = 1e30f;
#pragma unroll
    for (int k = 0; k < 8; ++k) {
        v0 = fminf(v0, pmin[g0 + (size_t)k * NROW]);
        v1 = fminf(v1, pmin[g1 + (size_t)k * NROW]);
    }
    float s = sqrtf(fmaxf(v0, 1e-12f)) + sqrtf(fmaxf(v1, 1e-12f));
    s += __shfl_xor(s, 1);
    s += __shfl_xor(s, 2);
    s += __shfl_xor(s, 4);
    s += __shfl_xor(s, 8);
    s += __shfl_xor(s, 16);
    s += __shfl_xor(s, 32);
    __shared__ float wsum[4];
    if ((threadIdx.x & 63) == 0) wsum[threadIdx.x >> 6] = s;
    __syncthreads();
    if (threadIdx.x == 0) {
        float bs = wsum[0] + wsum[1] + wsum[2] + wsum[3];
        unsigned long long q = (unsigned long long)((double)bs * 16777216.0); // 2^24 fixed pt
        atomicAdd(acc, q);
        __threadfence();
        unsigned long long done = atomicAdd(acc + 1, 1ull);
        if (done == 361) {
            __threadfence();
            unsigned long long total = atomicAdd(acc, 0ull);
            out[0] = (float)((double)total * (0x1p-24 / (64.0 * 1448.0)));
        }
    }
}

extern "C" void kernel_launch(void* const* d_in, const int* in_sizes, int n_in,
                              void* d_out, int out_size, void* d_ws, size_t ws_size,
                              hipStream_t stream) {
    const float* inp    = (const float*)d_in[0];
    const float* tgt    = (const float*)d_in[1];
    const int*   labels = (const int*)d_in[2];
    const float* muL    = (const float*)d_in[3];
    const float* deltaL = (const float*)d_in[4];
    const float* muR    = (const float*)d_in[5];
    const float* deltaR = (const float*)d_in[6];
    float* out = (float*)d_out;

    char* ws = (char*)d_ws;
    float* latT = (float*)ws;                                    // 128 KB
    float* pts3 = (float*)(ws + (128 << 10));                    // 2224128 B
    float* pmin = (float*)(ws + (128 << 10) + 2224128);          // 8*185344*4 = 5931008 B
    unsigned long long* acc = (unsigned long long*)(ws + (128 << 10) + 2224128 + 5931008);

    hipLaunchKernelGGL(pool_kernel, dim3(2048), dim3(256), 0, stream, inp, tgt, latT, acc);
    hipLaunchKernelGGL(decode_kernel, dim3(68, 2, 2), dim3(256), 0, stream,
                       latT, muL, deltaL, muR, deltaR, labels, pts3);
    hipLaunchKernelGGL(chamfer_kernel, dim3(8, 64, 2), dim3(128), 0, stream,
                       pts3, pmin);
    hipLaunchKernelGGL(combine_kernel, dim3(362), dim3(256), 0, stream, pmin, acc, out);
}

// Round 6
// 66.913 us; speedup vs baseline: 1.1068x; 1.0026x over previous
//
#include <hip/hip_runtime.h>

#define NV 1448
#define JD 4344    // 3*NV
#define CC 256
#define BB 64
#define QQ 128     // 2*BB
#define SLICE 181  // NV/8 cols per chamfer block (8*181=1448)
#define PAIRS 91   // ceil(SLICE/2), last pair padded with duplicate col
#define NROW (2 * BB * NV)  // 185344 row-slots
#define RPT 12     // rows per thread (128*12=1536 >= 1448)

// ---------------------------------------------------------------------------
// K1: global average pool -> latT[c][q], q = t*64+b. Thread 0 zeroes acc.
// ---------------------------------------------------------------------------
__global__ __launch_bounds__(256) void pool_kernel(const float* __restrict__ inp,
                                                   const float* __restrict__ tgt,
                                                   float* __restrict__ latT,
                                                   unsigned long long* __restrict__ acc) {
    int gid  = blockIdx.x * 256 + threadIdx.x;
    if (gid == 0) { acc[0] = 0ull; acc[1] = 0ull; }
    int lane = gid & 15;
    int row  = gid >> 4;
    if (row >= 2 * BB * CC) return;
    int t  = row >> 14;
    int bc = row & 16383;
    const float* src = (t ? tgt : inp) + (size_t)bc * 64;
    float4 v = reinterpret_cast<const float4*>(src)[lane];
    float s = (v.x + v.y) + (v.z + v.w);
    s += __shfl_xor(s, 1);
    s += __shfl_xor(s, 2);
    s += __shfl_xor(s, 4);
    s += __shfl_xor(s, 8);
    if (lane == 0) {
        int b = bc >> 8, c = bc & 255;
        latT[c * QQ + t * BB + b] = s * (1.0f / 64.0f);
    }
}

// ---------------------------------------------------------------------------
// K2: decode GEMM (unchanged from R5), 4j x 4q register blocking.
// ---------------------------------------------------------------------------
__global__ __launch_bounds__(256) void decode_kernel(const float* __restrict__ latT,
                                                     const float* __restrict__ muL,
                                                     const float* __restrict__ deltaL,
                                                     const float* __restrict__ muR,
                                                     const float* __restrict__ deltaR,
                                                     const int* __restrict__ labels,
                                                     float* __restrict__ pts3) {
    const int jt = blockIdx.x;                 // 68 tiles of 64 j
    const int L  = blockIdx.y;
    const int qh = blockIdx.z;                 // q half: 64 q's
    const float* __restrict__ delta = L ? deltaR : deltaL;
    const float* __restrict__ mu    = L ? muR : muL;
    const int j0  = jt * 64;
    const int tid = threadIdx.x;
    const int jl  = tid & 15;
    const int qg  = tid >> 4;                  // 0..15

    __shared__ float AsT[32][64];              // [k][j]
    __shared__ float Bs[32][64];               // [k][q]

    float acc[4][4];
#pragma unroll
    for (int u = 0; u < 4; ++u)
#pragma unroll
        for (int v = 0; v < 4; ++v) acc[u][v] = 0.f;

    const int sj = tid & 63;                   // stage: j-lane
    const int sk = (tid >> 6) * 8;             // stage: k-base (0,8,16,24)
    const float4* latT4 = reinterpret_cast<const float4*>(latT);

    for (int kc = 0; kc < CC; kc += 32) {
        __syncthreads();
        {   // stage AsT: 64 j x 32 k
            int j = j0 + sj;
            float4 v0 = make_float4(0.f, 0.f, 0.f, 0.f), v1 = v0;
            if (j < JD) {
                const float4* dp = reinterpret_cast<const float4*>(delta + (size_t)j * CC + kc + sk);
                v0 = dp[0]; v1 = dp[1];
            }
            AsT[sk + 0][sj] = v0.x; AsT[sk + 1][sj] = v0.y;
            AsT[sk + 2][sj] = v0.z; AsT[sk + 3][sj] = v0.w;
            AsT[sk + 4][sj] = v1.x; AsT[sk + 5][sj] = v1.y;
            AsT[sk + 6][sj] = v1.z; AsT[sk + 7][sj] = v1.w;
        }
        {   // stage Bs: 32 k x 64 q = 512 float4, 2 per thread
            int k  = tid >> 4;                 // 0..15
            int qi = tid & 15;
            reinterpret_cast<float4*>(&Bs[k][0])[qi]      = latT4[(size_t)(kc + k) * 32 + qh * 16 + qi];
            reinterpret_cast<float4*>(&Bs[k + 16][0])[qi] = latT4[(size_t)(kc + k + 16) * 32 + qh * 16 + qi];
        }
        __syncthreads();

#pragma unroll
        for (int k4 = 0; k4 < 32; k4 += 4) {
#pragma unroll
            for (int kk = 0; kk < 4; ++kk) {
                float4 a = *reinterpret_cast<const float4*>(&AsT[k4 + kk][jl * 4]);
                float4 b = *reinterpret_cast<const float4*>(&Bs[k4 + kk][qg * 4]);
                float av[4] = {a.x, a.y, a.z, a.w};
                float bv[4] = {b.x, b.y, b.z, b.w};
#pragma unroll
                for (int u = 0; u < 4; ++u)
#pragma unroll
                    for (int v = 0; v < 4; ++v)
                        acc[u][v] = fmaf(av[u], bv[v], acc[u][v]);
            }
        }
    }

    int j = j0 + jl * 4;
    if (j < JD) {
        float4 m = *reinterpret_cast<const float4*>(mu + j);
        float mu4[4] = {m.x, m.y, m.z, m.w};
#pragma unroll
        for (int v = 0; v < 4; ++v) {
            int q = qh * 64 + qg * 4 + v;
            int b = q & 63;
            if (labels[b] == L) {
                float4 o = make_float4(acc[0][v] + mu4[0], acc[1][v] + mu4[1],
                                       acc[2][v] + mu4[2], acc[3][v] + mu4[3]);
                *reinterpret_cast<float4*>(pts3 + (size_t)q * JD + j) = o;
            }
        }
    }
}

// ---------------------------------------------------------------------------
// K3: chamfer with packed v_pk_fma_f32 — 2 columns per VALU issue slot.
// B slice staged SoA as float2 pairs: (-2x,-2y,-2z,|b|^2); broadcast b64
// reads (all lanes same addr -> conflict-free). A duplicated into float2
// regs. Per 2 pairs: 3 pk_fma + 1 min3 (~1.75 issue/pair vs 3.5 scalar).
// |a|^2 added at epilogue. grid (slice,b,dir) = 1024 blocks x 128 thr.
// ---------------------------------------------------------------------------
__global__ __launch_bounds__(128) void chamfer_kernel(const float* __restrict__ pts3,
                                                      float* __restrict__ pmin) {
    const int slice = blockIdx.x;
    const int b     = blockIdx.y;
    const int dir   = blockIdx.z;
    const int qa = dir * BB + b;
    const int qb = (1 - dir) * BB + b;
    const float* __restrict__ A3 = pts3 + (size_t)qa * JD;
    const float* __restrict__ B3 = pts3 + (size_t)qb * JD + slice * (SLICE * 3);

    __shared__ float Bsx[2 * PAIRS], Bsy[2 * PAIRS], Bsz[2 * PAIRS], Bsw[2 * PAIRS];
    const int tid = threadIdx.x;
    for (int i = tid; i < SLICE; i += 128) {
        float x = B3[3 * i], y = B3[3 * i + 1], z = B3[3 * i + 2];
        float w = fmaf(x, x, fmaf(y, y, z * z));
        Bsx[i] = -2.f * x; Bsy[i] = -2.f * y; Bsz[i] = -2.f * z; Bsw[i] = w;
        if (i == SLICE - 1) {  // pad: duplicate last col so PAIRS*2 is full
            Bsx[i + 1] = -2.f * x; Bsy[i + 1] = -2.f * y;
            Bsz[i + 1] = -2.f * z; Bsw[i + 1] = w;
        }
    }
    __syncthreads();

    float2 ax[RPT], ay[RPT], az[RPT];
    float aw[RPT], mn[RPT];
#pragma unroll
    for (int r = 0; r < RPT; ++r) {
        int row = tid + 128 * r;
        bool v = row < NV;
        float x = v ? A3[3 * row]     : 0.f;
        float y = v ? A3[3 * row + 1] : 0.f;
        float z = v ? A3[3 * row + 2] : 0.f;
        ax[r] = make_float2(x, x); ay[r] = make_float2(y, y); az[r] = make_float2(z, z);
        aw[r] = fmaf(x, x, fmaf(y, y, z * z));
        mn[r] = 1e30f;
    }

    for (int m = 0; m < PAIRS; ++m) {
        float2 bx = *reinterpret_cast<const float2*>(Bsx + 2 * m);
        float2 by = *reinterpret_cast<const float2*>(Bsy + 2 * m);
        float2 bz = *reinterpret_cast<const float2*>(Bsz + 2 * m);
        float2 bw = *reinterpret_cast<const float2*>(Bsw + 2 * m);
#pragma unroll
        for (int r = 0; r < RPT; ++r) {
            float2 t;
            asm("v_pk_fma_f32 %0, %1, %2, %3" : "=v"(t) : "v"(bz), "v"(az[r]), "v"(bw));
            asm("v_pk_fma_f32 %0, %1, %2, %0" : "+v"(t) : "v"(by), "v"(ay[r]));
            asm("v_pk_fma_f32 %0, %1, %2, %0" : "+v"(t) : "v"(bx), "v"(ax[r]));
            mn[r] = fminf(fminf(mn[r], t.x), t.y);   // -> v_min3_f32
        }
    }

    float* dst = pmin + (size_t)slice * NROW + (size_t)qa * NV;
#pragma unroll
    for (int r = 0; r < RPT; ++r) {
        int row = tid + 128 * r;
        if (row < NV) dst[row] = mn[r] + aw[r];
    }
}

// ---------------------------------------------------------------------------
// K4: combine 8 slice-mins, sqrt, block sums -> exact fixed-point atomic
// accumulate (order-independent => deterministic); last block writes out.
// ---------------------------------------------------------------------------
__global__ __launch_bounds__(256) void combine_kernel(const float* __restrict__ pmin,
                                                      unsigned long long* __restrict__ acc,
                                                      float* __restrict__ out) {
    int g0 = blockIdx.x * 512 + threadIdx.x;
    int g1 = g0 + 256;
    float v0 = 1e30f, v1 = 1e30f;
#pragma unroll
    for (int k = 0; k < 8; ++k) {
        v0 = fminf(v0, pmin[g0 + (size_t)k * NROW]);
        v1 = fminf(v1, pmin[g1 + (size_t)k * NROW]);
    }
    float s = sqrtf(fmaxf(v0, 1e-12f)) + sqrtf(fmaxf(v1, 1e-12f));
    s += __shfl_xor(s, 1);
    s += __shfl_xor(s, 2);
    s += __shfl_xor(s, 4);
    s += __shfl_xor(s, 8);
    s += __shfl_xor(s, 16);
    s += __shfl_xor(s, 32);
    __shared__ float wsum[4];
    if ((threadIdx.x & 63) == 0) wsum[threadIdx.x >> 6] = s;
    __syncthreads();
    if (threadIdx.x == 0) {
        float bs = wsum[0] + wsum[1] + wsum[2] + wsum[3];
        unsigned long long q = (unsigned long long)((double)bs * 16777216.0); // 2^24 fixed pt
        atomicAdd(acc, q);
        __threadfence();
        unsigned long long done = atomicAdd(acc + 1, 1ull);
        if (done == 361) {
            __threadfence();
            unsigned long long total = atomicAdd(acc, 0ull);
            out[0] = (float)((double)total * (0x1p-24 / (64.0 * 1448.0)));
        }
    }
}

extern "C" void kernel_launch(void* const* d_in, const int* in_sizes, int n_in,
                              void* d_out, int out_size, void* d_ws, size_t ws_size,
                              hipStream_t stream) {
    const float* inp    = (const float*)d_in[0];
    const float* tgt    = (const float*)d_in[1];
    const int*   labels = (const int*)d_in[2];
    const float* muL    = (const float*)d_in[3];
    const float* deltaL = (const float*)d_in[4];
    const float* muR    = (const float*)d_in[5];
    const float* deltaR = (const float*)d_in[6];
    float* out = (float*)d_out;

    char* ws = (char*)d_ws;
    float* latT = (float*)ws;                                    // 128 KB
    float* pts3 = (float*)(ws + (128 << 10));                    // 2224128 B
    float* pmin = (float*)(ws + (128 << 10) + 2224128);          // 8*185344*4 = 5931008 B
    unsigned long long* acc = (unsigned long long*)(ws + (128 << 10) + 2224128 + 5931008);

    hipLaunchKernelGGL(pool_kernel, dim3(2048), dim3(256), 0, stream, inp, tgt, latT, acc);
    hipLaunchKernelGGL(decode_kernel, dim3(68, 2, 2), dim3(256), 0, stream,
                       latT, muL, deltaL, muR, deltaR, labels, pts3);
    hipLaunchKernelGGL(chamfer_kernel, dim3(8, 64, 2), dim3(128), 0, stream,
                       pts3, pmin);
    hipLaunchKernelGGL(combine_kernel, dim3(362), dim3(256), 0, stream, pmin, acc, out);
}